// Round 2
// baseline (1186.795 us; speedup 1.0000x reference)
//
#include <hip/hip_runtime.h>
#include <cstdint>
#include <initializer_list>

#define BATCH 32
#define LSEQ 1024
#define DDIM 1024

typedef unsigned short u16;
typedef unsigned int u32;
typedef __bf16 bf16x8 __attribute__((ext_vector_type(8)));
typedef float f32x4 __attribute__((ext_vector_type(4)));

__device__ __forceinline__ u16 f2bf(float f) {
  u32 u = __float_as_uint(f);
  u32 r = (u + 0x7FFFu + ((u >> 16) & 1u)) >> 16;
  return (u16)r;
}
__device__ __forceinline__ float bf2f(u16 h) {
  return __uint_as_float(((u32)h) << 16);
}

// async global->LDS, 16B per lane. LDS dest = wave-uniform base + lane*16.
__device__ __forceinline__ void gload_lds16(const void* g, void* l) {
  __builtin_amdgcn_global_load_lds(
      (__attribute__((address_space(1))) void*)(uintptr_t)g,
      (__attribute__((address_space(3))) void*)(u32)(uintptr_t)l,
      16, 0, 0);
}

// ---------------- fp32 -> bf16 convert (vectorized x4) ----------------
__global__ __launch_bounds__(256) void cvt_kernel(const float* __restrict__ in,
                                                  u16* __restrict__ out, int n4) {
  int i = blockIdx.x * 256 + threadIdx.x;
  if (i >= n4) return;
  float4 f = ((const float4*)in)[i];
  ushort4 o;
  o.x = f2bf(f.x); o.y = f2bf(f.y); o.z = f2bf(f.z); o.w = f2bf(f.w);
  ((ushort4*)out)[i] = o;
}

// ---------------- per-batch transpose + convert: [L,D] f32 -> [D,L] bf16 ----
__global__ __launch_bounds__(256) void transpose_cv(const float* __restrict__ in,
                                                    u16* __restrict__ outT) {
  __shared__ u16 tile[64][65];
  size_t boff = (size_t)blockIdx.z * (LSEQ * DDIM);
  int k0 = blockIdx.x * 64;  // L index
  int d0 = blockIdx.y * 64;  // D index
  int tx = threadIdx.x & 63;
  int ty = threadIdx.x >> 6;
#pragma unroll
  for (int r = ty; r < 64; r += 4)
    tile[r][tx] = f2bf(in[boff + (size_t)(k0 + r) * DDIM + d0 + tx]);
  __syncthreads();
#pragma unroll
  for (int r = ty; r < 64; r += 4)
    outT[boff + (size_t)(d0 + r) * LSEQ + k0 + tx] = tile[tx][r];
}

// ---------------- v[k] = sum_d context[k,d]*Wv[d]  (rows local to group) ----
__global__ __launch_bounds__(256) void rowdot_kernel(const float* __restrict__ x,
                                                     const float* __restrict__ w,
                                                     float* __restrict__ out) {
  int row = blockIdx.x;
  const float* p = x + (size_t)row * DDIM;
  int tid = threadIdx.x;
  float4 a = ((const float4*)p)[tid];
  float4 ww = ((const float4*)w)[tid];
  float s = a.x * ww.x + a.y * ww.y + a.z * ww.z + a.w * ww.w;
#pragma unroll
  for (int o = 32; o; o >>= 1) s += __shfl_xor(s, o);
  __shared__ float r[4];
  if ((tid & 63) == 0) r[tid >> 6] = s;
  __syncthreads();
  if (tid == 0) out[row] = (r[0] + r[1]) + (r[2] + r[3]);
}

// ---------------- generic NT GEMM: C = A @ B^T (+bias)(tanh) -------------
// A [M,K] bf16 row-major (dual pointer: k<ksplit from A1, else A2 at k-ksplit)
// B [N,K] bf16 row-major (row stride ldb), C [M,N] fp32 or bf16.
// 128x128 tile, BK=32, 4 waves (each 64x64 via 4x4 frags of 16x16x32 MFMA).
template <int OUT_F32, int HAS_BIAS, int DO_TANH>
__global__ __launch_bounds__(256) void gemm_nt(
    const u16* __restrict__ A1, const u16* __restrict__ A2, int ksplit,
    const u16* __restrict__ Bw, const float* __restrict__ bias,
    void* __restrict__ Cout, int K, int lda, int ldb, int ldc,
    long long sA, long long sB, long long sC) {
  __shared__ u16 As[4096];
  __shared__ u16 Bs[4096];

  const int tid = threadIdx.x;
  const int lane = tid & 63;
  const int wid = tid >> 6;
  const int wm = wid >> 1;
  const int wn = wid & 1;
  const int bz = blockIdx.z;
  const int m0 = blockIdx.y * 128;
  const int n0 = blockIdx.x * 128;

  const u16* a1 = A1 + (size_t)bz * sA;
  const u16* a2 = A2 + (size_t)bz * sA;
  const u16* bw = Bw + (size_t)bz * sB;

  const int srow = wid * 16 + (lane >> 2);  // staging row within 64-row half
  const int skof = (lane & 3) * 8;          // staging k offset (8 bf16 = 16B)

  f32x4 acc[4][4] = {};

  for (int k0 = 0; k0 < K; k0 += 32) {
    const u16* ab;
    int kk;
    if (k0 < ksplit) { ab = a1; kk = k0; } else { ab = a2; kk = k0 - ksplit; }
    const u16* asrc = ab + (size_t)(m0 + srow) * lda + kk + skof;
    const u16* bsrc = bw + (size_t)(n0 + srow) * ldb + k0 + skof;
    gload_lds16(asrc, &As[wid * 512]);
    gload_lds16(asrc + (size_t)64 * lda, &As[2048 + wid * 512]);
    gload_lds16(bsrc, &Bs[wid * 512]);
    gload_lds16(bsrc + (size_t)64 * ldb, &Bs[2048 + wid * 512]);
    __syncthreads();

    bf16x8 af[4], bfv[4];
#pragma unroll
    for (int i = 0; i < 4; ++i) {
      af[i] = *(const bf16x8*)&As[(wm * 64 + i * 16 + (lane & 15)) * 32 + (lane >> 4) * 8];
      bfv[i] = *(const bf16x8*)&Bs[(wn * 64 + i * 16 + (lane & 15)) * 32 + (lane >> 4) * 8];
    }
#pragma unroll
    for (int i = 0; i < 4; ++i)
#pragma unroll
      for (int j = 0; j < 4; ++j)
        acc[i][j] = __builtin_amdgcn_mfma_f32_16x16x32_bf16(af[i], bfv[j], acc[i][j], 0, 0, 0);
    __syncthreads();
  }

  const int crow = (lane >> 4) * 4;
  const int ccol = lane & 15;
#pragma unroll
  for (int i = 0; i < 4; ++i) {
#pragma unroll
    for (int j = 0; j < 4; ++j) {
      int r0 = m0 + wm * 64 + i * 16 + crow;
      int c = n0 + wn * 64 + j * 16 + ccol;
      float bb = HAS_BIAS ? bias[c] : 0.f;
#pragma unroll
      for (int t = 0; t < 4; ++t) {
        float v = acc[i][j][t] + bb;
        if (DO_TANH) v = tanhf(v);
        size_t idx = (size_t)bz * sC + (size_t)(r0 + t) * ldc + c;
        if (OUT_F32)
          ((float*)Cout)[idx] = v;
        else
          ((u16*)Cout)[idx] = f2bf(v);
      }
    }
  }
}

// ---------------- softmax over keys with +v bias and mask (group-local) ----
__global__ __launch_bounds__(256) void softmax_rows(const float* __restrict__ logits,
                                                    const float* __restrict__ vbias,
                                                    const int* __restrict__ amask,
                                                    u16* __restrict__ P) {
  const int row = blockIdx.x;  // blocal*L + q
  const int b = row >> 10;
  const float* lg = logits + (size_t)row * LSEQ;
  u16* prow = P + (size_t)row * LSEQ;
  const int tid = threadIdx.x;
  float x[4];
  int mk[4];
  float vmax = -3.0e38f;
#pragma unroll
  for (int i = 0; i < 4; ++i) {
    int k = tid + i * 256;
    mk[i] = amask[(b << 10) + k];
    x[i] = lg[k] + vbias[(b << 10) + k];
    if (!mk[i]) x[i] = -3.0e38f;
    vmax = fmaxf(vmax, x[i]);
  }
#pragma unroll
  for (int o = 32; o; o >>= 1) vmax = fmaxf(vmax, __shfl_xor(vmax, o));
  __shared__ float sred[4];
  if ((tid & 63) == 0) sred[tid >> 6] = vmax;
  __syncthreads();
  vmax = fmaxf(fmaxf(sred[0], sred[1]), fmaxf(sred[2], sred[3]));
  float s = 0.f, e[4];
#pragma unroll
  for (int i = 0; i < 4; ++i) {
    e[i] = mk[i] ? __expf(x[i] - vmax) : 0.f;
    s += e[i];
  }
#pragma unroll
  for (int o = 32; o; o >>= 1) s += __shfl_xor(s, o);
  __shared__ float ssum[4];
  if ((tid & 63) == 0) ssum[tid >> 6] = s;
  __syncthreads();
  s = (ssum[0] + ssum[1]) + (ssum[2] + ssum[3]);
  float inv = 1.f / s;
#pragma unroll
  for (int i = 0; i < 4; ++i) prow[tid + i * 256] = f2bf(e[i] * inv);
}

// ---------------- masked pooling, stage 1 (group-local batches) ----------
__global__ __launch_bounds__(256) void pool_partial(const u16* __restrict__ outfc,
                                                    const int* __restrict__ amask,
                                                    float* __restrict__ partial,
                                                    float* __restrict__ pcount) {
  int d = blockIdx.x * 256 + threadIdx.x;
  int qc = blockIdx.y;
  int b = blockIdx.z;  // local batch
  const u16* base = outfc + (((size_t)b * LSEQ + qc * 128) * DDIM) + d;
  const int* mrow = amask + b * LSEQ + qc * 128;
  float s = 0.f;
  int cnt = 0;
  for (int q = 0; q < 128; ++q) {
    if (mrow[q]) {
      s += bf2f(base[(size_t)q * DDIM]);
      cnt++;
    }
  }
  partial[((size_t)b * 8 + qc) * DDIM + d] = s;
  if (threadIdx.x == 0 && blockIdx.x == 0) pcount[b * 8 + qc] = (float)cnt;
}

// ---------------- pooling, stage 2: reduce chunks, divide by length --------
__global__ __launch_bounds__(256) void pool_final(const float* __restrict__ partial,
                                                  const float* __restrict__ pcount,
                                                  float* __restrict__ out) {
  int idx = blockIdx.x * 256 + threadIdx.x;  // b*D + d
  int b = idx >> 10;
  int d = idx & 1023;
  float s = 0.f, len = 0.f;
#pragma unroll
  for (int qc = 0; qc < 8; ++qc) {
    s += partial[((size_t)b * 8 + qc) * DDIM + d];
    len += pcount[b * 8 + qc];
  }
  out[idx] = s / len;
}

extern "C" void kernel_launch(void* const* d_in, const int* in_sizes, int n_in,
                              void* d_out, int out_size, void* d_ws, size_t ws_size,
                              hipStream_t stream) {
  const float* output = (const float*)d_in[0];
  const float* context = (const float*)d_in[1];
  const int* amask = (const int*)d_in[2];
  const float* Wo = (const float*)d_in[3];
  const float* bo = (const float*)d_in[4];
  const float* Wc = (const float*)d_in[5];
  const float* bc = (const float*)d_in[6];
  const float* Wb = (const float*)d_in[7];
  // d_in[8] Wu, d_in[9] bu, d_in[11] bv: constant per softmax row -> cancel
  const float* Wv = (const float*)d_in[10];
  const float* Wf = (const float*)d_in[12];
  const float* bfb = (const float*)d_in[13];
  float* out = (float*)d_out;
  (void)n_in; (void)in_sizes; (void)out_size;

  // ---- choose batch-group size G so workspace fits ws_size ----
  const size_t LD2 = (size_t)LSEQ * DDIM * 2;  // one batch of bf16 [L,D] = 2 MiB
  int G = 1;
  for (int g : {32, 16, 8, 4, 2, 1}) {
    size_t fixedb = (3 * 2 + 4 + 1) * (size_t)(1 << 20) + 64 * 1024;  // weights+partial+slack
    size_t need = fixedb + (size_t)g * (6 * LD2 + (size_t)LSEQ * LSEQ * 4 + LSEQ * 4 + 2048);
    if (need <= ws_size) { G = g; break; }
  }
  const int NG = BATCH / G;

  char* ws = (char*)d_ws;
  size_t off = 0;
  auto alloc = [&](size_t bytes) {
    char* p = ws + off;
    off += (bytes + 255) & ~(size_t)255;
    return p;
  };
  u16* wo_bf = (u16*)alloc((size_t)DDIM * DDIM * 2);
  u16* wc_bf = (u16*)alloc((size_t)DDIM * DDIM * 2);
  u16* wb_bf = (u16*)alloc((size_t)DDIM * DDIM * 2);
  u16* wf_bf = (u16*)alloc((size_t)DDIM * 2 * DDIM * 2);
  float* partial = (float*)alloc((size_t)BATCH * 8 * DDIM * 4);
  float* pcount = (float*)alloc((size_t)BATCH * 8 * 4);
  // per-group buffers (reused across groups)
  u16* out_g = (u16*)alloc((size_t)G * LD2);   // output bf16
  u16* cm_g = (u16*)alloc((size_t)G * LD2);    // context bf16, then mix
  u16* ctxT_g = (u16*)alloc((size_t)G * LD2);  // context^T bf16
  u16* opf_g = (u16*)alloc((size_t)G * LD2);   // o_t, then P, then fc-out
  u16* ct_g = (u16*)alloc((size_t)G * LD2);    // c_t
  u16* bq_g = (u16*)alloc((size_t)G * LD2);    // bilinear(o_t)
  float* logits = (float*)alloc((size_t)G * LSEQ * LSEQ * 4);
  float* vbuf = (float*)alloc((size_t)G * LSEQ * 4);

  dim3 blk(256);
  const long long M1 = (long long)LSEQ * DDIM;
  const int BIG = 1 << 30;

  // weight conversions (once)
  cvt_kernel<<<dim3(1024), blk, 0, stream>>>(Wo, wo_bf, DDIM * DDIM / 4);
  cvt_kernel<<<dim3(1024), blk, 0, stream>>>(Wc, wc_bf, DDIM * DDIM / 4);
  cvt_kernel<<<dim3(1024), blk, 0, stream>>>(Wb, wb_bf, DDIM * DDIM / 4);
  cvt_kernel<<<dim3(2048), blk, 0, stream>>>(Wf, wf_bf, DDIM * 2 * DDIM / 4);

  for (int grp = 0; grp < NG; ++grp) {
    const int gb = grp * G;  // first global batch of this group
    const float* outp = output + (size_t)gb * LSEQ * DDIM;
    const float* ctxp = context + (size_t)gb * LSEQ * DDIM;
    const int* amp = amask + (size_t)gb * LSEQ;
    const int n4 = G * LSEQ * DDIM / 4;

    cvt_kernel<<<dim3(n4 / 256), blk, 0, stream>>>(outp, out_g, n4);
    cvt_kernel<<<dim3(n4 / 256), blk, 0, stream>>>(ctxp, cm_g, n4);
    transpose_cv<<<dim3(16, 16, G), blk, 0, stream>>>(ctxp, ctxT_g);
    rowdot_kernel<<<dim3(G * LSEQ), blk, 0, stream>>>(ctxp, Wv, vbuf);

    // o_t = output @ Wo^T + bo
    gemm_nt<0, 1, 0><<<dim3(8, G * 8, 1), blk, 0, stream>>>(
        out_g, out_g, BIG, wo_bf, bo, opf_g, 1024, 1024, 1024, 1024, 0, 0, 0);
    // c_t = context @ Wc^T + bc
    gemm_nt<0, 1, 0><<<dim3(8, G * 8, 1), blk, 0, stream>>>(
        cm_g, cm_g, BIG, wc_bf, bc, ct_g, 1024, 1024, 1024, 1024, 0, 0, 0);
    // bq = o_t @ Wb^T
    gemm_nt<0, 0, 0><<<dim3(8, G * 8, 1), blk, 0, stream>>>(
        opf_g, opf_g, BIG, wb_bf, nullptr, bq_g, 1024, 1024, 1024, 1024, 0, 0, 0);
    // logits[b] = bq[b] @ c_t[b]^T   (batched over local b)
    gemm_nt<1, 0, 0><<<dim3(8, 8, G), blk, 0, stream>>>(
        bq_g, bq_g, BIG, ct_g, nullptr, logits, 1024, 1024, 1024, 1024, M1, M1, M1);
    // P = softmax(logits + v + mask) -> bf16 into opf_g (o_t dead)
    softmax_rows<<<dim3(G * LSEQ), blk, 0, stream>>>(logits, vbuf, amp, opf_g);
    // mix[b] = P[b] @ ctxT[b]^T -> into cm_g (ctx bf16 dead)
    gemm_nt<0, 0, 0><<<dim3(8, 8, G), blk, 0, stream>>>(
        opf_g, opf_g, BIG, ctxT_g, nullptr, cm_g, 1024, 1024, 1024, 1024, M1, M1, M1);
    // fc: tanh([output, mix] @ Wf^T + bf) -> bf16 into opf_g (P dead)
    gemm_nt<0, 1, 1><<<dim3(8, G * 8, 1), blk, 0, stream>>>(
        out_g, cm_g, 1024, wf_bf, bfb, opf_g, 2048, 1024, 2048, 1024, 0, 0, 0);
    // masked pooling partials (global batch offset gb)
    pool_partial<<<dim3(4, 8, G), blk, 0, stream>>>(
        opf_g, amp, partial + (size_t)gb * 8 * DDIM, pcount + (size_t)gb * 8);
  }
  pool_final<<<dim3(128), blk, 0, stream>>>(partial, pcount, out);
}

// Round 3
// 826.150 us; speedup vs baseline: 1.4365x; 1.4365x over previous
//
#include <hip/hip_runtime.h>
#include <cstdint>
#include <initializer_list>

#define BATCH 32
#define LSEQ 1024
#define DDIM 1024

typedef unsigned short u16;
typedef unsigned int u32;
typedef __bf16 bf16x8 __attribute__((ext_vector_type(8)));
typedef float f32x4 __attribute__((ext_vector_type(4)));

__device__ __forceinline__ u16 f2bf(float f) {
  u32 u = __float_as_uint(f);
  u32 r = (u + 0x7FFFu + ((u >> 16) & 1u)) >> 16;
  return (u16)r;
}
__device__ __forceinline__ float bf2f(u16 h) {
  return __uint_as_float(((u32)h) << 16);
}

__device__ __forceinline__ void gload_lds16(const void* g, void* l) {
  __builtin_amdgcn_global_load_lds(
      (__attribute__((address_space(1))) void*)(uintptr_t)g,
      (__attribute__((address_space(3))) void*)(u32)(uintptr_t)l,
      16, 0, 0);
}

// ---------------- fp32 -> bf16 convert (vectorized x4) ----------------
__global__ __launch_bounds__(256) void cvt_kernel(const float* __restrict__ in,
                                                  u16* __restrict__ out, int n4) {
  int i = blockIdx.x * 256 + threadIdx.x;
  if (i >= n4) return;
  float4 f = ((const float4*)in)[i];
  ushort4 o;
  o.x = f2bf(f.x); o.y = f2bf(f.y); o.z = f2bf(f.z); o.w = f2bf(f.w);
  ((ushort4*)out)[i] = o;
}

// ------- transpose+convert [L,D]f32 -> [D,L]bf16, optional [L,D]bf16 copy ---
__global__ __launch_bounds__(256) void transpose_cv(const float* __restrict__ in,
                                                    u16* __restrict__ outT,
                                                    u16* __restrict__ outN) {
  __shared__ u16 tile[64][65];
  size_t boff = (size_t)blockIdx.z * (LSEQ * DDIM);
  int k0 = blockIdx.x * 64;  // L index
  int d0 = blockIdx.y * 64;  // D index
  int tx = threadIdx.x & 63;
  int ty = threadIdx.x >> 6;
#pragma unroll
  for (int r = ty; r < 64; r += 4) {
    u16 h = f2bf(in[boff + (size_t)(k0 + r) * DDIM + d0 + tx]);
    tile[r][tx] = h;
    if (outN) outN[boff + (size_t)(k0 + r) * DDIM + d0 + tx] = h;
  }
  __syncthreads();
#pragma unroll
  for (int r = ty; r < 64; r += 4)
    outT[boff + (size_t)(d0 + r) * LSEQ + k0 + tx] = tile[tx][r];
}

// ---------------- out[row] = x[row,:]  dot  w[:]  (fp32) ----------------
__global__ __launch_bounds__(256) void rowdot_kernel(const float* __restrict__ x,
                                                     const float* __restrict__ w,
                                                     float* __restrict__ out) {
  int row = blockIdx.x;
  const float* p = x + (size_t)row * DDIM;
  int tid = threadIdx.x;
  float4 a = ((const float4*)p)[tid];
  float4 ww = ((const float4*)w)[tid];
  float s = a.x * ww.x + a.y * ww.y + a.z * ww.z + a.w * ww.w;
#pragma unroll
  for (int o = 32; o; o >>= 1) s += __shfl_xor(s, o);
  __shared__ float r[4];
  if ((tid & 63) == 0) r[tid >> 6] = s;
  __syncthreads();
  if (tid == 0) out[row] = (r[0] + r[1]) + (r[2] + r[3]);
}

// ---- wv2[d] = Wv[d] + sum_e bbo[e] * Wc[e,d]   (4 blocks x 256) ----
__global__ __launch_bounds__(256) void w2_kernel(const float* __restrict__ Wv,
                                                 const float* __restrict__ bbo,
                                                 const float* __restrict__ Wc,
                                                 float* __restrict__ wv2) {
  int d = blockIdx.x * 256 + threadIdx.x;
  float s = Wv[d];
  for (int e = 0; e < DDIM; ++e) s += bbo[e] * Wc[(size_t)e * DDIM + d];
  wv2[d] = s;
}

// ---------------- generic NT GEMM: C = A @ B^T (+bias)(tanh) -------------
// 1-D grid (nm*nn*nz blocks), XCD-aware decode (xcd = id % 8 assumption):
//  ZBATCH=1: one batch's blocks pinned to one XCD (nz%8==0), else id%nz.
//  ZBATCH=0: m-panels partitioned across XCDs, n walked fastest.
// A [M,K] bf16 (dual pointer: k<ksplit from A1, else A2 at k-ksplit)
// B [N,K] bf16 row stride ldb; C [M,N] fp32 or bf16.
// 128x128 tile, BK=32, 4 waves, 16x16x32 MFMA, global_load_lds staging.
template <int OUT_F32, int HAS_BIAS, int DO_TANH, int ZBATCH>
__global__ __launch_bounds__(256) void gemm_nt(
    const u16* __restrict__ A1, const u16* __restrict__ A2, int ksplit,
    const u16* __restrict__ Bw, const float* __restrict__ bias,
    void* __restrict__ Cout, int K, int lda, int ldb, int ldc,
    long long sA, long long sB, long long sC, int nm, int nn, int nz) {
  __shared__ u16 As[4096];
  __shared__ u16 Bs[4096];

  const int id = blockIdx.x;
  int bz, mb, nb;
  if (ZBATCH) {
    if ((nz & 7) == 0) {
      int x = id & 7;
      int j = id >> 3;
      int pb = nm * nn;
      bz = x + 8 * (j / pb);
      int in_ = j % pb;
      nb = in_ % nn;
      mb = in_ / nn;
    } else {
      bz = id % nz;
      int t = id / nz;
      nb = t % nn;
      mb = t / nn;
    }
  } else {
    bz = 0;
    int mg = id & 7;
    int t = id >> 3;
    int nmg = nm >> 3;  // nm % 8 == 0 required
    int ml = t / nn;
    nb = t % nn;
    mb = mg * nmg + ml;
  }

  const int tid = threadIdx.x;
  const int lane = tid & 63;
  const int wid = tid >> 6;
  const int wm = wid >> 1;
  const int wn = wid & 1;
  const int m0 = mb * 128;
  const int n0 = nb * 128;

  const u16* a1 = A1 + (size_t)bz * sA;
  const u16* a2 = A2 + (size_t)bz * sA;
  const u16* bw = Bw + (size_t)bz * sB;

  const int srow = wid * 16 + (lane >> 2);
  const int skof = (lane & 3) * 8;

  f32x4 acc[4][4] = {};

  for (int k0 = 0; k0 < K; k0 += 32) {
    const u16* ab;
    int kk;
    if (k0 < ksplit) { ab = a1; kk = k0; } else { ab = a2; kk = k0 - ksplit; }
    const u16* asrc = ab + (size_t)(m0 + srow) * lda + kk + skof;
    const u16* bsrc = bw + (size_t)(n0 + srow) * ldb + k0 + skof;
    gload_lds16(asrc, &As[wid * 512]);
    gload_lds16(asrc + (size_t)64 * lda, &As[2048 + wid * 512]);
    gload_lds16(bsrc, &Bs[wid * 512]);
    gload_lds16(bsrc + (size_t)64 * ldb, &Bs[2048 + wid * 512]);
    __syncthreads();

    bf16x8 af[4], bfv[4];
#pragma unroll
    for (int i = 0; i < 4; ++i) {
      af[i] = *(const bf16x8*)&As[(wm * 64 + i * 16 + (lane & 15)) * 32 + (lane >> 4) * 8];
      bfv[i] = *(const bf16x8*)&Bs[(wn * 64 + i * 16 + (lane & 15)) * 32 + (lane >> 4) * 8];
    }
#pragma unroll
    for (int i = 0; i < 4; ++i)
#pragma unroll
      for (int j = 0; j < 4; ++j)
        acc[i][j] = __builtin_amdgcn_mfma_f32_16x16x32_bf16(af[i], bfv[j], acc[i][j], 0, 0, 0);
    __syncthreads();
  }

  const int crow = (lane >> 4) * 4;
  const int ccol = lane & 15;
#pragma unroll
  for (int i = 0; i < 4; ++i) {
#pragma unroll
    for (int j = 0; j < 4; ++j) {
      int r0 = m0 + wm * 64 + i * 16 + crow;
      int c = n0 + wn * 64 + j * 16 + ccol;
      float bb = HAS_BIAS ? bias[c] : 0.f;
#pragma unroll
      for (int t = 0; t < 4; ++t) {
        float v = acc[i][j][t] + bb;
        if (DO_TANH) v = tanhf(v);
        size_t idx = (size_t)bz * sC + (size_t)(r0 + t) * ldc + c;
        if (OUT_F32)
          ((float*)Cout)[idx] = v;
        else
          ((u16*)Cout)[idx] = f2bf(v);
      }
    }
  }
}

// ---------------- softmax over keys with +v bias and mask (group-local) ----
__global__ __launch_bounds__(256) void softmax_rows(const float* __restrict__ logits,
                                                    const float* __restrict__ vbias,
                                                    const int* __restrict__ amask,
                                                    u16* __restrict__ P) {
  const int row = blockIdx.x;  // blocal*L + q
  const int b = row >> 10;
  const float* lg = logits + (size_t)row * LSEQ;
  u16* prow = P + (size_t)row * LSEQ;
  const int tid = threadIdx.x;
  float x[4];
  int mk[4];
  float vmax = -3.0e38f;
#pragma unroll
  for (int i = 0; i < 4; ++i) {
    int k = tid + i * 256;
    mk[i] = amask[(b << 10) + k];
    x[i] = lg[k] + vbias[(b << 10) + k];
    if (!mk[i]) x[i] = -3.0e38f;
    vmax = fmaxf(vmax, x[i]);
  }
#pragma unroll
  for (int o = 32; o; o >>= 1) vmax = fmaxf(vmax, __shfl_xor(vmax, o));
  __shared__ float sred[4];
  if ((tid & 63) == 0) sred[tid >> 6] = vmax;
  __syncthreads();
  vmax = fmaxf(fmaxf(sred[0], sred[1]), fmaxf(sred[2], sred[3]));
  float s = 0.f, e[4];
#pragma unroll
  for (int i = 0; i < 4; ++i) {
    e[i] = mk[i] ? __expf(x[i] - vmax) : 0.f;
    s += e[i];
  }
#pragma unroll
  for (int o = 32; o; o >>= 1) s += __shfl_xor(s, o);
  __shared__ float ssum[4];
  if ((tid & 63) == 0) ssum[tid >> 6] = s;
  __syncthreads();
  s = (ssum[0] + ssum[1]) + (ssum[2] + ssum[3]);
  float inv = 1.f / s;
#pragma unroll
  for (int i = 0; i < 4; ++i) prow[tid + i * 256] = f2bf(e[i] * inv);
}

// ---------------- masked pooling, stage 1 (group-local batches) ----------
__global__ __launch_bounds__(256) void pool_partial(const u16* __restrict__ outfc,
                                                    const int* __restrict__ amask,
                                                    float* __restrict__ partial,
                                                    float* __restrict__ pcount) {
  int d = blockIdx.x * 256 + threadIdx.x;
  int qc = blockIdx.y;
  int b = blockIdx.z;
  const u16* base = outfc + (((size_t)b * LSEQ + qc * 128) * DDIM) + d;
  const int* mrow = amask + b * LSEQ + qc * 128;
  float s = 0.f;
  int cnt = 0;
  for (int q = 0; q < 128; ++q) {
    if (mrow[q]) {
      s += bf2f(base[(size_t)q * DDIM]);
      cnt++;
    }
  }
  partial[((size_t)b * 8 + qc) * DDIM + d] = s;
  if (threadIdx.x == 0 && blockIdx.x == 0) pcount[b * 8 + qc] = (float)cnt;
}

__global__ __launch_bounds__(256) void pool_final(const float* __restrict__ partial,
                                                  const float* __restrict__ pcount,
                                                  float* __restrict__ out) {
  int idx = blockIdx.x * 256 + threadIdx.x;
  int b = idx >> 10;
  int d = idx & 1023;
  float s = 0.f, len = 0.f;
#pragma unroll
  for (int qc = 0; qc < 8; ++qc) {
    s += partial[((size_t)b * 8 + qc) * DDIM + d];
    len += pcount[b * 8 + qc];
  }
  out[idx] = s / len;
}

extern "C" void kernel_launch(void* const* d_in, const int* in_sizes, int n_in,
                              void* d_out, int out_size, void* d_ws, size_t ws_size,
                              hipStream_t stream) {
  const float* output = (const float*)d_in[0];
  const float* context = (const float*)d_in[1];
  const int* amask = (const int*)d_in[2];
  const float* Wo = (const float*)d_in[3];
  const float* bo = (const float*)d_in[4];
  const float* Wc = (const float*)d_in[5];
  // d_in[6] bc: constant per softmax row -> cancels
  const float* Wb = (const float*)d_in[7];
  // d_in[8] Wu, d_in[9] bu, d_in[11] bv: constant per softmax row -> cancel
  const float* Wv = (const float*)d_in[10];
  const float* Wf = (const float*)d_in[12];
  const float* bfb = (const float*)d_in[13];
  float* out = (float*)d_out;
  (void)n_in; (void)in_sizes; (void)out_size;

  // ---- choose batch-group size G so workspace fits ----
  const size_t LD2 = (size_t)LSEQ * DDIM * 2;  // 2 MiB
  const size_t fixed_b = (size_t)22 * (1 << 20);
  const size_t per_b = 4 * LD2 + (size_t)LSEQ * LSEQ * 4 + LSEQ * 4 + 4096;
  int G = 1;
  for (int g : {32, 16, 8, 4, 2, 1}) {
    if (fixed_b + (size_t)g * per_b <= ws_size) { G = g; break; }
  }
  const int NG = BATCH / G;

  char* ws = (char*)d_ws;
  size_t off = 0;
  auto alloc = [&](size_t bytes) {
    char* p = ws + off;
    off += (bytes + 255) & ~(size_t)255;
    return p;
  };
  const size_t W2 = (size_t)DDIM * DDIM * 2;
  u16* wb_bf = (u16*)alloc(W2);
  u16* wf_bf = (u16*)alloc(2 * W2);
  u16* woT_bf = (u16*)alloc(W2);
  u16* wcT_bf = (u16*)alloc(W2);
  u16* wboT_bf = (u16*)alloc(W2);   // (Wb@Wo)^T
  u16* mt_bf = (u16*)alloc(W2);     // M^T = Wc^T @ (Wb@Wo)
  float* bbo = (float*)alloc(DDIM * 4);
  float* wv2 = (float*)alloc(DDIM * 4);
  float* partial = (float*)alloc((size_t)BATCH * 8 * DDIM * 4);
  float* pcount = (float*)alloc((size_t)BATCH * 8 * 4);
  // per-group buffers
  u16* out_g = (u16*)alloc((size_t)G * LD2);   // output bf16
  u16* ctx_g = (u16*)alloc((size_t)G * LD2);   // context bf16, then mix
  u16* ctxT_g = (u16*)alloc((size_t)G * LD2);  // context^T bf16
  u16* y_g = (u16*)alloc((size_t)G * LD2);     // y=out@M, then P, then fc-out
  float* logits = (float*)alloc((size_t)G * LSEQ * LSEQ * 4);
  float* vbuf = (float*)alloc((size_t)G * LSEQ * 4);

  dim3 blk(256);
  const long long M1 = (long long)LSEQ * DDIM;
  const int BIG = 1 << 30;

  // ---- precompute: weights ----
  cvt_kernel<<<dim3(1024), blk, 0, stream>>>(Wb, wb_bf, DDIM * DDIM / 4);
  cvt_kernel<<<dim3(2048), blk, 0, stream>>>(Wf, wf_bf, DDIM * 2 * DDIM / 4);
  transpose_cv<<<dim3(16, 16, 1), blk, 0, stream>>>(Wo, woT_bf, nullptr);
  transpose_cv<<<dim3(16, 16, 1), blk, 0, stream>>>(Wc, wcT_bf, nullptr);
  rowdot_kernel<<<dim3(1024), blk, 0, stream>>>(Wb, bo, bbo);  // bbo = Wb@bo
  w2_kernel<<<dim3(4), blk, 0, stream>>>(Wv, bbo, Wc, wv2);    // wv2 = Wv + Wc^T@bbo
  // WboT = Wo^T @ Wb^T = NT(WoT, Wb)
  gemm_nt<0, 0, 0, 0><<<dim3(64), blk, 0, stream>>>(
      woT_bf, woT_bf, BIG, wb_bf, nullptr, wboT_bf,
      1024, 1024, 1024, 1024, 0, 0, 0, 8, 8, 1);
  // MT = Wc^T @ Wbo = NT(WcT, WboT)
  gemm_nt<0, 0, 0, 0><<<dim3(64), blk, 0, stream>>>(
      wcT_bf, wcT_bf, BIG, wboT_bf, nullptr, mt_bf,
      1024, 1024, 1024, 1024, 0, 0, 0, 8, 8, 1);

  for (int grp = 0; grp < NG; ++grp) {
    const int gb = grp * G;
    const float* outp = output + (size_t)gb * LSEQ * DDIM;
    const float* ctxp = context + (size_t)gb * LSEQ * DDIM;
    const int* amp = amask + (size_t)gb * LSEQ;
    const int n4 = G * LSEQ * DDIM / 4;

    cvt_kernel<<<dim3(n4 / 256), blk, 0, stream>>>(outp, out_g, n4);
    transpose_cv<<<dim3(16, 16, G), blk, 0, stream>>>(ctxp, ctxT_g, ctx_g);
    rowdot_kernel<<<dim3(G * LSEQ), blk, 0, stream>>>(ctxp, wv2, vbuf);

    // y = output @ M = NT(out_bf, MT)   [dense]
    gemm_nt<0, 0, 0, 0><<<dim3(G * 64), blk, 0, stream>>>(
        out_g, out_g, BIG, mt_bf, nullptr, y_g,
        1024, 1024, 1024, 1024, 0, 0, 0, G * 8, 8, 1);
    // logits[b] = y[b] @ ctx[b]^T   [batched, batch->XCD]
    gemm_nt<1, 0, 0, 1><<<dim3(G * 64), blk, 0, stream>>>(
        y_g, y_g, BIG, ctx_g, nullptr, logits,
        1024, 1024, 1024, 1024, M1, M1, M1, 8, 8, G);
    // P = softmax(logits + wv2.ctx + mask) -> bf16 into y_g
    softmax_rows<<<dim3(G * LSEQ), blk, 0, stream>>>(logits, vbuf, amp, y_g);
    // mix[b] = P[b] @ ctxT[b]^T -> into ctx_g
    gemm_nt<0, 0, 0, 1><<<dim3(G * 64), blk, 0, stream>>>(
        y_g, y_g, BIG, ctxT_g, nullptr, ctx_g,
        1024, 1024, 1024, 1024, M1, M1, M1, 8, 8, G);
    // fc: tanh([output, mix] @ Wf^T + bf) -> bf16 into y_g
    gemm_nt<0, 1, 1, 0><<<dim3(G * 64), blk, 0, stream>>>(
        out_g, ctx_g, 1024, wf_bf, bfb, y_g,
        2048, 1024, 2048, 1024, 0, 0, 0, G * 8, 8, 1);
    // masked pooling partials
    pool_partial<<<dim3(4, 8, G), blk, 0, stream>>>(
        y_g, amp, partial + (size_t)gb * 8 * DDIM, pcount + (size_t)gb * 8);
  }
  pool_final<<<dim3(128), blk, 0, stream>>>(partial, pcount, out);
}

// Round 4
// 720.284 us; speedup vs baseline: 1.6477x; 1.1470x over previous
//
#include <hip/hip_runtime.h>
#include <cstdint>
#include <initializer_list>

#define BATCH 32
#define LSEQ 1024
#define DDIM 1024

typedef unsigned short u16;
typedef unsigned int u32;
typedef __bf16 bf16x8 __attribute__((ext_vector_type(8)));
typedef float f32x4 __attribute__((ext_vector_type(4)));

__device__ __forceinline__ u16 f2bf(float f) {
  u32 u = __float_as_uint(f);
  u32 r = (u + 0x7FFFu + ((u >> 16) & 1u)) >> 16;
  return (u16)r;
}
__device__ __forceinline__ float bf2f(u16 h) {
  return __uint_as_float(((u32)h) << 16);
}

__device__ __forceinline__ void gload_lds16(const void* g, void* l) {
  __builtin_amdgcn_global_load_lds(
      (__attribute__((address_space(1))) void*)(uintptr_t)g,
      (__attribute__((address_space(3))) void*)(u32)(uintptr_t)l,
      16, 0, 0);
}

#define PHASE_BAR()                          \
  do {                                       \
    __builtin_amdgcn_sched_barrier(0);       \
    __builtin_amdgcn_s_barrier();            \
    __builtin_amdgcn_sched_barrier(0);       \
  } while (0)

// ---------------- fp32 -> bf16 convert (vectorized x4) ----------------
__global__ __launch_bounds__(256) void cvt_kernel(const float* __restrict__ in,
                                                  u16* __restrict__ out, int n4) {
  int i = blockIdx.x * 256 + threadIdx.x;
  if (i >= n4) return;
  float4 f = ((const float4*)in)[i];
  ushort4 o;
  o.x = f2bf(f.x); o.y = f2bf(f.y); o.z = f2bf(f.z); o.w = f2bf(f.w);
  ((ushort4*)out)[i] = o;
}

// ------- transpose+convert [L,D]f32 -> [D,L]bf16, optional [L,D]bf16 copy ---
__global__ __launch_bounds__(256) void transpose_cv(const float* __restrict__ in,
                                                    u16* __restrict__ outT,
                                                    u16* __restrict__ outN) {
  __shared__ u16 tile[64][65];
  size_t boff = (size_t)blockIdx.z * (LSEQ * DDIM);
  int k0 = blockIdx.x * 64;
  int d0 = blockIdx.y * 64;
  int tx = threadIdx.x & 63;
  int ty = threadIdx.x >> 6;
#pragma unroll
  for (int r = ty; r < 64; r += 4) {
    u16 h = f2bf(in[boff + (size_t)(k0 + r) * DDIM + d0 + tx]);
    tile[r][tx] = h;
    if (outN) outN[boff + (size_t)(k0 + r) * DDIM + d0 + tx] = h;
  }
  __syncthreads();
#pragma unroll
  for (int r = ty; r < 64; r += 4)
    outT[boff + (size_t)(d0 + r) * LSEQ + k0 + tx] = tile[tx][r];
}

// ---------------- out[row] = x[row,:] dot w[:]  (fp32) ----------------
__global__ __launch_bounds__(256) void rowdot_kernel(const float* __restrict__ x,
                                                     const float* __restrict__ w,
                                                     float* __restrict__ out) {
  int row = blockIdx.x;
  const float* p = x + (size_t)row * DDIM;
  int tid = threadIdx.x;
  float4 a = ((const float4*)p)[tid];
  float4 ww = ((const float4*)w)[tid];
  float s = a.x * ww.x + a.y * ww.y + a.z * ww.z + a.w * ww.w;
#pragma unroll
  for (int o = 32; o; o >>= 1) s += __shfl_xor(s, o);
  __shared__ float r[4];
  if ((tid & 63) == 0) r[tid >> 6] = s;
  __syncthreads();
  if (tid == 0) out[row] = (r[0] + r[1]) + (r[2] + r[3]);
}

// ---- wv2[d] = Wv[d] + sum_e bbo[e] * Wc[e,d] ----
__global__ __launch_bounds__(256) void w2_kernel(const float* __restrict__ Wv,
                                                 const float* __restrict__ bbo,
                                                 const float* __restrict__ Wc,
                                                 float* __restrict__ wv2) {
  int d = blockIdx.x * 256 + threadIdx.x;
  float s = Wv[d];
  for (int e = 0; e < DDIM; ++e) s += bbo[e] * Wc[(size_t)e * DDIM + d];
  wv2[d] = s;
}

// ============ small 128x128 2-phase GEMM (weight precompute only) ===========
template <int OUT_F32, int HAS_BIAS, int DO_TANH, int ZBATCH>
__global__ __launch_bounds__(256) void gemm_nt(
    const u16* __restrict__ A1, const u16* __restrict__ A2, int ksplit,
    const u16* __restrict__ Bw, const float* __restrict__ bias,
    void* __restrict__ Cout, int K, int lda, int ldb, int ldc,
    long long sA, long long sB, long long sC, int nm, int nn, int nz) {
  __shared__ u16 As[4096];
  __shared__ u16 Bs[4096];

  const int id = blockIdx.x;
  int bz, mb, nb;
  if (ZBATCH) {
    if ((nz & 7) == 0) {
      int x = id & 7; int j = id >> 3; int pb = nm * nn;
      bz = x + 8 * (j / pb);
      int in_ = j % pb; nb = in_ % nn; mb = in_ / nn;
    } else { bz = id % nz; int t = id / nz; nb = t % nn; mb = t / nn; }
  } else {
    bz = 0;
    if ((nm & 7) == 0) {
      int mg = id & 7; int t = id >> 3; int nmg = nm >> 3;
      nb = t % nn; mb = mg * nmg + t / nn;
    } else { nb = id % nn; mb = id / nn; }
  }

  const int tid = threadIdx.x;
  const int lane = tid & 63;
  const int wid = tid >> 6;
  const int wm = wid >> 1;
  const int wn = wid & 1;
  const int m0 = mb * 128;
  const int n0 = nb * 128;

  const u16* a1 = A1 + (size_t)bz * sA;
  const u16* a2 = A2 + (size_t)bz * sA;
  const u16* bw = Bw + (size_t)bz * sB;

  const int srow = wid * 16 + (lane >> 2);
  const int skof = (lane & 3) * 8;

  f32x4 acc[4][4] = {};

  for (int k0 = 0; k0 < K; k0 += 32) {
    const u16* ab; int kk;
    if (k0 < ksplit) { ab = a1; kk = k0; } else { ab = a2; kk = k0 - ksplit; }
    const u16* asrc = ab + (size_t)(m0 + srow) * lda + kk + skof;
    const u16* bsrc = bw + (size_t)(n0 + srow) * ldb + k0 + skof;
    gload_lds16(asrc, &As[wid * 512]);
    gload_lds16(asrc + (size_t)64 * lda, &As[2048 + wid * 512]);
    gload_lds16(bsrc, &Bs[wid * 512]);
    gload_lds16(bsrc + (size_t)64 * ldb, &Bs[2048 + wid * 512]);
    __syncthreads();

    bf16x8 af[4], bfv[4];
#pragma unroll
    for (int i = 0; i < 4; ++i) {
      af[i] = *(const bf16x8*)&As[(wm * 64 + i * 16 + (lane & 15)) * 32 + (lane >> 4) * 8];
      bfv[i] = *(const bf16x8*)&Bs[(wn * 64 + i * 16 + (lane & 15)) * 32 + (lane >> 4) * 8];
    }
#pragma unroll
    for (int i = 0; i < 4; ++i)
#pragma unroll
      for (int j = 0; j < 4; ++j)
        acc[i][j] = __builtin_amdgcn_mfma_f32_16x16x32_bf16(af[i], bfv[j], acc[i][j], 0, 0, 0);
    __syncthreads();
  }

  const int crow = (lane >> 4) * 4;
  const int ccol = lane & 15;
#pragma unroll
  for (int i = 0; i < 4; ++i) {
#pragma unroll
    for (int j = 0; j < 4; ++j) {
      int r0 = m0 + wm * 64 + i * 16 + crow;
      int c = n0 + wn * 64 + j * 16 + ccol;
      float bb = HAS_BIAS ? bias[c] : 0.f;
#pragma unroll
      for (int t = 0; t < 4; ++t) {
        float v = acc[i][j][t] + bb;
        if (DO_TANH) v = tanhf(v);
        size_t idx = (size_t)bz * sC + (size_t)(r0 + t) * ldc + c;
        if (OUT_F32) ((float*)Cout)[idx] = v;
        else ((u16*)Cout)[idx] = f2bf(v);
      }
    }
  }
}

// ============ 256x256 deep-pipelined GEMM (8 waves, BK=32, 3 LDS bufs) ======
// C = A @ B^T (+bias)(tanh). A dual-pointer concat at ksplit.
// LDS layout per K-tile: A[16 subtiles][16][32] bf16 (st_16x32 swizzle via
// pre-swizzled global source + swizzled read), B same. 3 buffers, 2-tile
// prefetch lead, one counted s_waitcnt vmcnt(4) per K-tile.
template <int OUT_F32, int HAS_BIAS, int DO_TANH, int ZBATCH>
__global__ __launch_bounds__(512, 2) void gemm8(
    const u16* __restrict__ A1, const u16* __restrict__ A2, int ksplit,
    const u16* __restrict__ Bw, const float* __restrict__ bias,
    void* __restrict__ Cout, int K, int lda, int ldb, int ldc,
    long long sA, long long sB, long long sC, int nm, int nn, int nz) {
  __shared__ __align__(16) u16 lds[49152];  // 96 KiB: A 3x8192, B 3x8192 u16
  u16* ldsA = lds;
  u16* ldsB = lds + 24576;

  const int id = blockIdx.x;
  int bz, mb, nb;
  if (ZBATCH) {
    if ((nz & 7) == 0) {
      int x = id & 7; int j = id >> 3; int pb = nm * nn;
      bz = x + 8 * (j / pb);
      int in_ = j % pb; nb = in_ % nn; mb = in_ / nn;
    } else { bz = id % nz; int t = id / nz; nb = t % nn; mb = t / nn; }
  } else {
    bz = 0;
    if ((nm & 7) == 0) {
      int mg = id & 7; int t = id >> 3; int nmg = nm >> 3;
      nb = t % nn; mb = mg * nmg + t / nn;
    } else { nb = id % nn; mb = id / nn; }
  }

  const int tid = threadIdx.x;
  const int lane = tid & 63;
  const int wid = tid >> 6;  // 0..7
  const int wm = wid >> 2;   // 0..1 (M half)
  const int wn = wid & 3;    // 0..3 (N quarter)
  const int m0 = mb * 256;
  const int n0 = nb * 256;

  const u16* a1 = A1 + (size_t)bz * sA;
  const u16* a2 = A2 + (size_t)bz * sA;
  const u16* bw = Bw + (size_t)bz * sB;

  // staging geometry: wave stages subtiles {2*wid, 2*wid+1}; lane l covers
  // row (l>>2), cols ((l&3)*8) ^ ((l>>5)<<4)  [inverse st_16x32 swizzle]
  const int srow = lane >> 2;
  const int scol = ((lane & 3) * 8) ^ (((lane >> 5) & 1) << 4);
  const size_t aRowOff = (size_t)(m0 + wid * 32 + srow) * lda + scol;
  const size_t aRowOff2 = aRowOff + (size_t)16 * lda;
  const size_t bRowOff = (size_t)(n0 + wid * 32 + srow) * ldb + scol;
  const size_t bRowOff2 = bRowOff + (size_t)16 * ldb;
  u16* const ldsAw = ldsA + wid * 1024;  // subtile 2*wid base (512 u16 each)
  u16* const ldsBw = ldsB + wid * 1024;

  // fragment read geometry (swizzled): subtile-local u16 offset
  const int foff = (lane & 15) * 32 + ((((lane >> 4) * 8)) ^ ((lane & 8) ? 16 : 0));

  const int NT = K >> 5;  // K-tiles of 32

  f32x4 acc[8][4] = {};
  bf16x8 af[4], bfv[4];

#define STAGE_A(tt, bi)                                             \
  do {                                                              \
    int k0s = (tt) << 5;                                            \
    const u16* g; int gc;                                           \
    if (k0s < ksplit) { g = a1; gc = k0s; }                         \
    else { g = a2; gc = k0s - ksplit; }                             \
    u16* dst = ldsAw + (bi) * 8192;                                 \
    gload_lds16(g + aRowOff + gc, dst);                             \
    gload_lds16(g + aRowOff2 + gc, dst + 512);                      \
  } while (0)
#define STAGE_B(tt, bi)                                             \
  do {                                                              \
    int k0s = (tt) << 5;                                            \
    u16* dst = ldsBw + (bi) * 8192;                                 \
    gload_lds16(bw + bRowOff + k0s, dst);                           \
    gload_lds16(bw + bRowOff2 + k0s, dst + 512);                    \
  } while (0)

  // prologue: stage tiles 0,1 into bufs 0,1; wait tile 0 (allow tile 1 out)
  STAGE_A(0, 0); STAGE_B(0, 0);
  STAGE_A(1, 1); STAGE_B(1, 1);
  __builtin_amdgcn_sched_barrier(0);
  asm volatile("s_waitcnt vmcnt(4)" ::: "memory");
  PHASE_BAR();

  int cur = 0;
  for (int t = 0; t < NT; ++t) {
    const u16* Ab = ldsA + cur * 8192;
    const u16* Bb = ldsB + cur * 8192;
    const int nxt = (cur >= 1) ? cur - 1 : 2;  // (t+2)%3
    const bool st = (t + 2) < NT;

    // ---- phase 1: read A m-frags 0-3 + all B frags; stage A(t+2) ----
#pragma unroll
    for (int i = 0; i < 4; ++i)
      af[i] = *(const bf16x8*)(Ab + (wm * 8 + i) * 512 + foff);
#pragma unroll
    for (int j = 0; j < 4; ++j)
      bfv[j] = *(const bf16x8*)(Bb + (wn * 4 + j) * 512 + foff);
    if (st) STAGE_A(t + 2, nxt);
    PHASE_BAR();
    __builtin_amdgcn_s_setprio(1);
#pragma unroll
    for (int i = 0; i < 4; ++i)
#pragma unroll
      for (int j = 0; j < 4; ++j)
        acc[i][j] = __builtin_amdgcn_mfma_f32_16x16x32_bf16(af[i], bfv[j], acc[i][j], 0, 0, 0);
    __builtin_amdgcn_s_setprio(0);
    PHASE_BAR();

    // ---- phase 2: read A m-frags 4-7; stage B(t+2); counted vmcnt ----
#pragma unroll
    for (int i = 0; i < 4; ++i)
      af[i] = *(const bf16x8*)(Ab + (wm * 8 + 4 + i) * 512 + foff);
    if (st) STAGE_B(t + 2, nxt);
    PHASE_BAR();
    __builtin_amdgcn_s_setprio(1);
#pragma unroll
    for (int i = 0; i < 4; ++i)
#pragma unroll
      for (int j = 0; j < 4; ++j)
        acc[4 + i][j] = __builtin_amdgcn_mfma_f32_16x16x32_bf16(af[i], bfv[j], acc[4 + i][j], 0, 0, 0);
    __builtin_amdgcn_s_setprio(0);
    __builtin_amdgcn_sched_barrier(0);
    if (st)
      asm volatile("s_waitcnt vmcnt(4)" ::: "memory");
    else if (t + 1 < NT)
      asm volatile("s_waitcnt vmcnt(0)" ::: "memory");
    PHASE_BAR();

    cur = (cur < 2) ? cur + 1 : 0;
  }
#undef STAGE_A
#undef STAGE_B

  const int crow = (lane >> 4) * 4;
  const int ccol = lane & 15;
#pragma unroll
  for (int i = 0; i < 8; ++i) {
#pragma unroll
    for (int j = 0; j < 4; ++j) {
      int r0 = m0 + wm * 128 + i * 16 + crow;
      int c = n0 + wn * 64 + j * 16 + ccol;
      float bb = HAS_BIAS ? bias[c] : 0.f;
#pragma unroll
      for (int t = 0; t < 4; ++t) {
        float v = acc[i][j][t] + bb;
        if (DO_TANH) v = tanhf(v);
        size_t idx = (size_t)bz * sC + (size_t)(r0 + t) * ldc + c;
        if (OUT_F32) ((float*)Cout)[idx] = v;
        else ((u16*)Cout)[idx] = f2bf(v);
      }
    }
  }
}

// ---------------- softmax over keys with +v bias and mask ----------------
__global__ __launch_bounds__(256) void softmax_rows(const float* __restrict__ logits,
                                                    const float* __restrict__ vbias,
                                                    const int* __restrict__ amask,
                                                    u16* __restrict__ P) {
  const int row = blockIdx.x;
  const int b = row >> 10;
  const float* lg = logits + (size_t)row * LSEQ;
  u16* prow = P + (size_t)row * LSEQ;
  const int tid = threadIdx.x;
  float x[4];
  int mk[4];
  float vmax = -3.0e38f;
#pragma unroll
  for (int i = 0; i < 4; ++i) {
    int k = tid + i * 256;
    mk[i] = amask[(b << 10) + k];
    x[i] = lg[k] + vbias[(b << 10) + k];
    if (!mk[i]) x[i] = -3.0e38f;
    vmax = fmaxf(vmax, x[i]);
  }
#pragma unroll
  for (int o = 32; o; o >>= 1) vmax = fmaxf(vmax, __shfl_xor(vmax, o));
  __shared__ float sred[4];
  if ((tid & 63) == 0) sred[tid >> 6] = vmax;
  __syncthreads();
  vmax = fmaxf(fmaxf(sred[0], sred[1]), fmaxf(sred[2], sred[3]));
  float s = 0.f, e[4];
#pragma unroll
  for (int i = 0; i < 4; ++i) {
    e[i] = mk[i] ? __expf(x[i] - vmax) : 0.f;
    s += e[i];
  }
#pragma unroll
  for (int o = 32; o; o >>= 1) s += __shfl_xor(s, o);
  __shared__ float ssum[4];
  if ((tid & 63) == 0) ssum[tid >> 6] = s;
  __syncthreads();
  s = (ssum[0] + ssum[1]) + (ssum[2] + ssum[3]);
  float inv = 1.f / s;
#pragma unroll
  for (int i = 0; i < 4; ++i) prow[tid + i * 256] = f2bf(e[i] * inv);
}

// ---------------- masked pooling ----------------
__global__ __launch_bounds__(256) void pool_partial(const u16* __restrict__ outfc,
                                                    const int* __restrict__ amask,
                                                    float* __restrict__ partial,
                                                    float* __restrict__ pcount) {
  int d = blockIdx.x * 256 + threadIdx.x;
  int qc = blockIdx.y;
  int b = blockIdx.z;
  const u16* base = outfc + (((size_t)b * LSEQ + qc * 128) * DDIM) + d;
  const int* mrow = amask + b * LSEQ + qc * 128;
  float s = 0.f;
  int cnt = 0;
  for (int q = 0; q < 128; ++q) {
    if (mrow[q]) {
      s += bf2f(base[(size_t)q * DDIM]);
      cnt++;
    }
  }
  partial[((size_t)b * 8 + qc) * DDIM + d] = s;
  if (threadIdx.x == 0 && blockIdx.x == 0) pcount[b * 8 + qc] = (float)cnt;
}

__global__ __launch_bounds__(256) void pool_final(const float* __restrict__ partial,
                                                  const float* __restrict__ pcount,
                                                  float* __restrict__ out) {
  int idx = blockIdx.x * 256 + threadIdx.x;
  int b = idx >> 10;
  int d = idx & 1023;
  float s = 0.f, len = 0.f;
#pragma unroll
  for (int qc = 0; qc < 8; ++qc) {
    s += partial[((size_t)b * 8 + qc) * DDIM + d];
    len += pcount[b * 8 + qc];
  }
  out[idx] = s / len;
}

extern "C" void kernel_launch(void* const* d_in, const int* in_sizes, int n_in,
                              void* d_out, int out_size, void* d_ws, size_t ws_size,
                              hipStream_t stream) {
  const float* output = (const float*)d_in[0];
  const float* context = (const float*)d_in[1];
  const int* amask = (const int*)d_in[2];
  const float* Wo = (const float*)d_in[3];
  const float* bo = (const float*)d_in[4];
  const float* Wc = (const float*)d_in[5];
  const float* Wb = (const float*)d_in[7];
  const float* Wv = (const float*)d_in[10];
  const float* Wf = (const float*)d_in[12];
  const float* bfb = (const float*)d_in[13];
  float* out = (float*)d_out;
  (void)n_in; (void)in_sizes; (void)out_size;

  const size_t LD2 = (size_t)LSEQ * DDIM * 2;
  const size_t fixed_b = (size_t)22 * (1 << 20);
  const size_t per_b = 4 * LD2 + (size_t)LSEQ * LSEQ * 4 + LSEQ * 4 + 4096;
  int G = 1;
  for (int g : {32, 16, 8, 4, 2, 1}) {
    if (fixed_b + (size_t)g * per_b <= ws_size) { G = g; break; }
  }
  const int NG = BATCH / G;

  char* ws = (char*)d_ws;
  size_t off = 0;
  auto alloc = [&](size_t bytes) {
    char* p = ws + off;
    off += (bytes + 255) & ~(size_t)255;
    return p;
  };
  const size_t W2 = (size_t)DDIM * DDIM * 2;
  u16* wb_bf = (u16*)alloc(W2);
  u16* wf_bf = (u16*)alloc(2 * W2);
  u16* woT_bf = (u16*)alloc(W2);
  u16* wcT_bf = (u16*)alloc(W2);
  u16* wboT_bf = (u16*)alloc(W2);
  u16* mt_bf = (u16*)alloc(W2);
  float* bbo = (float*)alloc(DDIM * 4);
  float* wv2 = (float*)alloc(DDIM * 4);
  float* partial = (float*)alloc((size_t)BATCH * 8 * DDIM * 4);
  float* pcount = (float*)alloc((size_t)BATCH * 8 * 4);
  u16* out_g = (u16*)alloc((size_t)G * LD2);
  u16* ctx_g = (u16*)alloc((size_t)G * LD2);
  u16* ctxT_g = (u16*)alloc((size_t)G * LD2);
  u16* y_g = (u16*)alloc((size_t)G * LD2);
  float* logits = (float*)alloc((size_t)G * LSEQ * LSEQ * 4);
  float* vbuf = (float*)alloc((size_t)G * LSEQ * 4);

  dim3 blk(256), blk8(512);
  const long long M1 = (long long)LSEQ * DDIM;
  const int BIG = 1 << 30;

  // ---- weight precompute ----
  cvt_kernel<<<dim3(1024), blk, 0, stream>>>(Wb, wb_bf, DDIM * DDIM / 4);
  cvt_kernel<<<dim3(2048), blk, 0, stream>>>(Wf, wf_bf, DDIM * 2 * DDIM / 4);
  transpose_cv<<<dim3(16, 16, 1), blk, 0, stream>>>(Wo, woT_bf, nullptr);
  transpose_cv<<<dim3(16, 16, 1), blk, 0, stream>>>(Wc, wcT_bf, nullptr);
  rowdot_kernel<<<dim3(1024), blk, 0, stream>>>(Wb, bo, bbo);
  w2_kernel<<<dim3(4), blk, 0, stream>>>(Wv, bbo, Wc, wv2);
  gemm_nt<0, 0, 0, 0><<<dim3(64), blk, 0, stream>>>(
      woT_bf, woT_bf, BIG, wb_bf, nullptr, wboT_bf,
      1024, 1024, 1024, 1024, 0, 0, 0, 8, 8, 1);
  gemm_nt<0, 0, 0, 0><<<dim3(64), blk, 0, stream>>>(
      wcT_bf, wcT_bf, BIG, wboT_bf, nullptr, mt_bf,
      1024, 1024, 1024, 1024, 0, 0, 0, 8, 8, 1);

  for (int grp = 0; grp < NG; ++grp) {
    const int gb = grp * G;
    const float* outp = output + (size_t)gb * LSEQ * DDIM;
    const float* ctxp = context + (size_t)gb * LSEQ * DDIM;
    const int* amp = amask + (size_t)gb * LSEQ;
    const int n4 = G * LSEQ * DDIM / 4;

    cvt_kernel<<<dim3(n4 / 256), blk, 0, stream>>>(outp, out_g, n4);
    transpose_cv<<<dim3(16, 16, G), blk, 0, stream>>>(ctxp, ctxT_g, ctx_g);
    rowdot_kernel<<<dim3(G * LSEQ), blk, 0, stream>>>(ctxp, wv2, vbuf);

    // y = output @ M
    gemm8<0, 0, 0, 0><<<dim3(G * 16), blk8, 0, stream>>>(
        out_g, out_g, BIG, mt_bf, nullptr, y_g,
        1024, 1024, 1024, 1024, 0, 0, 0, G * 4, 4, 1);
    // logits[b] = y[b] @ ctx[b]^T
    gemm8<1, 0, 0, 1><<<dim3(G * 16), blk8, 0, stream>>>(
        y_g, y_g, BIG, ctx_g, nullptr, logits,
        1024, 1024, 1024, 1024, M1, M1, M1, 4, 4, G);
    // P = softmax(logits + wv2.ctx + mask) -> bf16 into y_g
    softmax_rows<<<dim3(G * LSEQ), blk, 0, stream>>>(logits, vbuf, amp, y_g);
    // mix[b] = P[b] @ ctxT[b]^T -> into ctx_g
    gemm8<0, 0, 0, 1><<<dim3(G * 16), blk8, 0, stream>>>(
        y_g, y_g, BIG, ctxT_g, nullptr, ctx_g,
        1024, 1024, 1024, 1024, M1, M1, M1, 4, 4, G);
    // fc: tanh([output, mix] @ Wf^T + bf) -> bf16 into y_g
    gemm8<0, 1, 1, 0><<<dim3(G * 16), blk8, 0, stream>>>(
        out_g, ctx_g, 1024, wf_bf, bfb, y_g,
        2048, 1024, 2048, 1024, 0, 0, 0, G * 4, 4, 1);
    pool_partial<<<dim3(4, 8, G), blk, 0, stream>>>(
        y_g, amp, partial + (size_t)gb * 8 * DDIM, pcount + (size_t)gb * 8);
  }
  pool_final<<<dim3(128), blk, 0, stream>>>(partial, pcount, out);
}

// Round 5
// 709.014 us; speedup vs baseline: 1.6739x; 1.0159x over previous
//
#include <hip/hip_runtime.h>
#include <cstdint>
#include <initializer_list>

#define BATCH 32
#define LSEQ 1024
#define DDIM 1024

typedef unsigned short u16;
typedef unsigned int u32;
typedef __bf16 bf16x8 __attribute__((ext_vector_type(8)));
typedef float f32x4 __attribute__((ext_vector_type(4)));

__device__ __forceinline__ u16 f2bf(float f) {
  u32 u = __float_as_uint(f);
  u32 r = (u + 0x7FFFu + ((u >> 16) & 1u)) >> 16;
  return (u16)r;
}
__device__ __forceinline__ float bf2f(u16 h) {
  return __uint_as_float(((u32)h) << 16);
}

__device__ __forceinline__ void gload_lds16(const void* g, void* l) {
  __builtin_amdgcn_global_load_lds(
      (__attribute__((address_space(1))) void*)(uintptr_t)g,
      (__attribute__((address_space(3))) void*)(u32)(uintptr_t)l,
      16, 0, 0);
}

// ---------------- fp32 -> bf16 convert (vectorized x4) ----------------
__global__ __launch_bounds__(256) void cvt_kernel(const float* __restrict__ in,
                                                  u16* __restrict__ out, int n4) {
  int i = blockIdx.x * 256 + threadIdx.x;
  if (i >= n4) return;
  float4 f = ((const float4*)in)[i];
  ushort4 o;
  o.x = f2bf(f.x); o.y = f2bf(f.y); o.z = f2bf(f.z); o.w = f2bf(f.w);
  ((ushort4*)out)[i] = o;
}

// ------- transpose+convert [L,D]f32 -> [D,L]bf16, optional [L,D]bf16 copy ---
__global__ __launch_bounds__(256) void transpose_cv(const float* __restrict__ in,
                                                    u16* __restrict__ outT,
                                                    u16* __restrict__ outN) {
  __shared__ u16 tile[64][65];
  size_t boff = (size_t)blockIdx.z * (LSEQ * DDIM);
  int k0 = blockIdx.x * 64;
  int d0 = blockIdx.y * 64;
  int tx = threadIdx.x & 63;
  int ty = threadIdx.x >> 6;
#pragma unroll
  for (int r = ty; r < 64; r += 4) {
    u16 h = f2bf(in[boff + (size_t)(k0 + r) * DDIM + d0 + tx]);
    tile[r][tx] = h;
    if (outN) outN[boff + (size_t)(k0 + r) * DDIM + d0 + tx] = h;
  }
  __syncthreads();
#pragma unroll
  for (int r = ty; r < 64; r += 4)
    outT[boff + (size_t)(d0 + r) * LSEQ + k0 + tx] = tile[tx][r];
}

// ---------------- out[row] = x[row,:] dot w[:]  (fp32) ----------------
__global__ __launch_bounds__(256) void rowdot_kernel(const float* __restrict__ x,
                                                     const float* __restrict__ w,
                                                     float* __restrict__ out) {
  int row = blockIdx.x;
  const float* p = x + (size_t)row * DDIM;
  int tid = threadIdx.x;
  float4 a = ((const float4*)p)[tid];
  float4 ww = ((const float4*)w)[tid];
  float s = a.x * ww.x + a.y * ww.y + a.z * ww.z + a.w * ww.w;
#pragma unroll
  for (int o = 32; o; o >>= 1) s += __shfl_xor(s, o);
  __shared__ float r[4];
  if ((tid & 63) == 0) r[tid >> 6] = s;
  __syncthreads();
  if (tid == 0) out[row] = (r[0] + r[1]) + (r[2] + r[3]);
}

// ---- wv2[d] = Wv[d] + sum_e bbo[e] * Wc[e,d] ----
__global__ __launch_bounds__(256) void w2_kernel(const float* __restrict__ Wv,
                                                 const float* __restrict__ bbo,
                                                 const float* __restrict__ Wc,
                                                 float* __restrict__ wv2) {
  int d = blockIdx.x * 256 + threadIdx.x;
  float s = Wv[d];
  for (int e = 0; e < DDIM; ++e) s += bbo[e] * Wc[(size_t)e * DDIM + d];
  wv2[d] = s;
}

// ============ small 128x128 2-phase GEMM (weight precompute only) ===========
template <int OUT_F32, int HAS_BIAS, int DO_TANH, int ZBATCH>
__global__ __launch_bounds__(256) void gemm_nt(
    const u16* __restrict__ A1, const u16* __restrict__ A2, int ksplit,
    const u16* __restrict__ Bw, const float* __restrict__ bias,
    void* __restrict__ Cout, int K, int lda, int ldb, int ldc,
    long long sA, long long sB, long long sC, int nm, int nn, int nz) {
  __shared__ u16 As[4096];
  __shared__ u16 Bs[4096];

  const int id = blockIdx.x;
  int bz, mb, nb;
  if (ZBATCH) {
    if ((nz & 7) == 0) {
      int x = id & 7; int j = id >> 3; int pb = nm * nn;
      bz = x + 8 * (j / pb);
      int in_ = j % pb; nb = in_ % nn; mb = in_ / nn;
    } else { bz = id % nz; int t = id / nz; nb = t % nn; mb = t / nn; }
  } else {
    bz = 0;
    if ((nm & 7) == 0) {
      int mg = id & 7; int t = id >> 3; int nmg = nm >> 3;
      nb = t % nn; mb = mg * nmg + t / nn;
    } else { nb = id % nn; mb = id / nn; }
  }

  const int tid = threadIdx.x;
  const int lane = tid & 63;
  const int wid = tid >> 6;
  const int wm = wid >> 1;
  const int wn = wid & 1;
  const int m0 = mb * 128;
  const int n0 = nb * 128;

  const u16* a1 = A1 + (size_t)bz * sA;
  const u16* a2 = A2 + (size_t)bz * sA;
  const u16* bw = Bw + (size_t)bz * sB;

  const int srow = wid * 16 + (lane >> 2);
  const int skof = (lane & 3) * 8;

  f32x4 acc[4][4] = {};

  for (int k0 = 0; k0 < K; k0 += 32) {
    const u16* ab; int kk;
    if (k0 < ksplit) { ab = a1; kk = k0; } else { ab = a2; kk = k0 - ksplit; }
    const u16* asrc = ab + (size_t)(m0 + srow) * lda + kk + skof;
    const u16* bsrc = bw + (size_t)(n0 + srow) * ldb + k0 + skof;
    gload_lds16(asrc, &As[wid * 512]);
    gload_lds16(asrc + (size_t)64 * lda, &As[2048 + wid * 512]);
    gload_lds16(bsrc, &Bs[wid * 512]);
    gload_lds16(bsrc + (size_t)64 * ldb, &Bs[2048 + wid * 512]);
    __syncthreads();

    bf16x8 af[4], bfv[4];
#pragma unroll
    for (int i = 0; i < 4; ++i) {
      af[i] = *(const bf16x8*)&As[(wm * 64 + i * 16 + (lane & 15)) * 32 + (lane >> 4) * 8];
      bfv[i] = *(const bf16x8*)&Bs[(wn * 64 + i * 16 + (lane & 15)) * 32 + (lane >> 4) * 8];
    }
#pragma unroll
    for (int i = 0; i < 4; ++i)
#pragma unroll
      for (int j = 0; j < 4; ++j)
        acc[i][j] = __builtin_amdgcn_mfma_f32_16x16x32_bf16(af[i], bfv[j], acc[i][j], 0, 0, 0);
    __syncthreads();
  }

  const int crow = (lane >> 4) * 4;
  const int ccol = lane & 15;
#pragma unroll
  for (int i = 0; i < 4; ++i) {
#pragma unroll
    for (int j = 0; j < 4; ++j) {
      int r0 = m0 + wm * 64 + i * 16 + crow;
      int c = n0 + wn * 64 + j * 16 + ccol;
      float bb = HAS_BIAS ? bias[c] : 0.f;
#pragma unroll
      for (int t = 0; t < 4; ++t) {
        float v = acc[i][j][t] + bb;
        if (DO_TANH) v = tanhf(v);
        size_t idx = (size_t)bz * sC + (size_t)(r0 + t) * ldc + c;
        if (OUT_F32) ((float*)Cout)[idx] = v;
        else ((u16*)Cout)[idx] = f2bf(v);
      }
    }
  }
}

// ========= 256x256 pipelined GEMM: 8 waves, BK=32, 3 NAMED buffer pairs =====
// One barrier per phase; counted vmcnt(4) once per K-tile; st_16x32 swizzle
// via pre-swizzled global source (linear LDS dest) + swizzled ds_read.
template <int OUT_F32, int HAS_BIAS, int DO_TANH, int ZBATCH>
__global__ __launch_bounds__(512, 2) void gemm256(
    const u16* __restrict__ A1, const u16* __restrict__ A2, int ksplit,
    const u16* __restrict__ Bw, const float* __restrict__ bias,
    void* __restrict__ Cout, int K, int lda, int ldb, int ldc,
    long long sA, long long sB, long long sC, int nm, int nn, int nz) {
  // 6 distinct LDS objects so alias analysis can separate DMA vs ds_read
  __shared__ __align__(16) u16 As0[8192];
  __shared__ __align__(16) u16 As1[8192];
  __shared__ __align__(16) u16 As2[8192];
  __shared__ __align__(16) u16 Bs0[8192];
  __shared__ __align__(16) u16 Bs1[8192];
  __shared__ __align__(16) u16 Bs2[8192];

  const int id = blockIdx.x;
  int bz, mb, nb;
  if (ZBATCH) {
    if ((nz & 7) == 0) {
      int x = id & 7; int j = id >> 3; int pb = nm * nn;
      bz = x + 8 * (j / pb);
      int in_ = j % pb; nb = in_ % nn; mb = in_ / nn;
    } else { bz = id % nz; int t = id / nz; nb = t % nn; mb = t / nn; }
  } else {
    bz = 0;
    if ((nm & 7) == 0) {
      int mg = id & 7; int t = id >> 3; int nmg = nm >> 3;
      nb = t % nn; mb = mg * nmg + t / nn;
    } else { nb = id % nn; mb = id / nn; }
  }

  const int tid = threadIdx.x;
  const int lane = tid & 63;
  const int wid = tid >> 6;  // 0..7
  const int wm = wid >> 2;   // 0..1 : M half (128 rows)
  const int wn = wid & 3;    // 0..3 : N quarter (64 cols)
  const int m0 = mb * 256;
  const int n0 = nb * 256;

  const u16* a1 = A1 + (size_t)bz * sA;
  const u16* a2 = A2 + (size_t)bz * sA;
  const u16* bw = Bw + (size_t)bz * sB;

  // cooperative staging: thread covers subtiles s0=wid, s1=wid+8 (rows 16s..)
  const int s0 = wid;
  const int s1 = wid + 8;
  const int strow = lane >> 2;
  const int stcol = ((lane & 3) * 8) ^ (((lane >> 5) & 1) << 4);  // inv swizzle
  const size_t aOff0 = (size_t)(m0 + 16 * s0 + strow) * lda + stcol;
  const size_t aOff1 = (size_t)(m0 + 16 * s1 + strow) * lda + stcol;
  const size_t bOff0 = (size_t)(n0 + 16 * s0 + strow) * ldb + stcol;
  const size_t bOff1 = (size_t)(n0 + 16 * s1 + strow) * ldb + stcol;

  // fragment read: subtile rb*512 + foff (swizzled)
  const int foff = (lane & 15) * 32 + (((lane >> 4) * 8) ^ ((lane & 8) ? 16 : 0));

  const int NT = K >> 5;

  f32x4 acc[8][4] = {};

#define STAGE_A(tt, Abuf)                                        \
  do {                                                           \
    int k0s = (tt) << 5;                                         \
    const u16* g; int gc;                                        \
    if (k0s < ksplit) { g = a1; gc = k0s; }                      \
    else { g = a2; gc = k0s - ksplit; }                          \
    gload_lds16(g + aOff0 + gc, Abuf + (size_t)s0 * 512);        \
    gload_lds16(g + aOff1 + gc, Abuf + (size_t)s1 * 512);        \
  } while (0)
#define STAGE_B(tt, Bbuf)                                        \
  do {                                                           \
    int k0s = (tt) << 5;                                         \
    gload_lds16(bw + bOff0 + k0s, Bbuf + (size_t)s0 * 512);      \
    gload_lds16(bw + bOff1 + k0s, Bbuf + (size_t)s1 * 512);      \
  } while (0)

  // TILE body: 2 phases, one barrier per phase, vmcnt(4) at tile end.
#define TILE(t, Ab, Bb, An, Bn)                                               \
  do {                                                                        \
    bf16x8 a0, a1r, a2r, a3, b0, b1, b2, b3;                                  \
    /* phase A: A-frags 0-3 + all B-frags; stage A(t+2) */                    \
    a0 = *(const bf16x8*)(Ab + (wm * 8 + 0) * 512 + foff);                    \
    a1r = *(const bf16x8*)(Ab + (wm * 8 + 1) * 512 + foff);                   \
    a2r = *(const bf16x8*)(Ab + (wm * 8 + 2) * 512 + foff);                   \
    a3 = *(const bf16x8*)(Ab + (wm * 8 + 3) * 512 + foff);                    \
    b0 = *(const bf16x8*)(Bb + (wn * 4 + 0) * 512 + foff);                    \
    b1 = *(const bf16x8*)(Bb + (wn * 4 + 1) * 512 + foff);                    \
    b2 = *(const bf16x8*)(Bb + (wn * 4 + 2) * 512 + foff);                    \
    b3 = *(const bf16x8*)(Bb + (wn * 4 + 3) * 512 + foff);                    \
    if ((t) + 2 < NT) STAGE_A((t) + 2, An);                                   \
    __builtin_amdgcn_s_barrier();                                             \
    asm volatile("s_waitcnt lgkmcnt(0)" ::: "memory");                        \
    __builtin_amdgcn_s_setprio(1);                                            \
    acc[0][0] = __builtin_amdgcn_mfma_f32_16x16x32_bf16(a0, b0, acc[0][0], 0, 0, 0); \
    acc[0][1] = __builtin_amdgcn_mfma_f32_16x16x32_bf16(a0, b1, acc[0][1], 0, 0, 0); \
    acc[0][2] = __builtin_amdgcn_mfma_f32_16x16x32_bf16(a0, b2, acc[0][2], 0, 0, 0); \
    acc[0][3] = __builtin_amdgcn_mfma_f32_16x16x32_bf16(a0, b3, acc[0][3], 0, 0, 0); \
    acc[1][0] = __builtin_amdgcn_mfma_f32_16x16x32_bf16(a1r, b0, acc[1][0], 0, 0, 0); \
    acc[1][1] = __builtin_amdgcn_mfma_f32_16x16x32_bf16(a1r, b1, acc[1][1], 0, 0, 0); \
    acc[1][2] = __builtin_amdgcn_mfma_f32_16x16x32_bf16(a1r, b2, acc[1][2], 0, 0, 0); \
    acc[1][3] = __builtin_amdgcn_mfma_f32_16x16x32_bf16(a1r, b3, acc[1][3], 0, 0, 0); \
    acc[2][0] = __builtin_amdgcn_mfma_f32_16x16x32_bf16(a2r, b0, acc[2][0], 0, 0, 0); \
    acc[2][1] = __builtin_amdgcn_mfma_f32_16x16x32_bf16(a2r, b1, acc[2][1], 0, 0, 0); \
    acc[2][2] = __builtin_amdgcn_mfma_f32_16x16x32_bf16(a2r, b2, acc[2][2], 0, 0, 0); \
    acc[2][3] = __builtin_amdgcn_mfma_f32_16x16x32_bf16(a2r, b3, acc[2][3], 0, 0, 0); \
    acc[3][0] = __builtin_amdgcn_mfma_f32_16x16x32_bf16(a3, b0, acc[3][0], 0, 0, 0); \
    acc[3][1] = __builtin_amdgcn_mfma_f32_16x16x32_bf16(a3, b1, acc[3][1], 0, 0, 0); \
    acc[3][2] = __builtin_amdgcn_mfma_f32_16x16x32_bf16(a3, b2, acc[3][2], 0, 0, 0); \
    acc[3][3] = __builtin_amdgcn_mfma_f32_16x16x32_bf16(a3, b3, acc[3][3], 0, 0, 0); \
    __builtin_amdgcn_s_setprio(0);                                            \
    /* phase B: A-frags 4-7 (B reused); stage B(t+2); counted vmcnt */        \
    a0 = *(const bf16x8*)(Ab + (wm * 8 + 4) * 512 + foff);                    \
    a1r = *(const bf16x8*)(Ab + (wm * 8 + 5) * 512 + foff);                   \
    a2r = *(const bf16x8*)(Ab + (wm * 8 + 6) * 512 + foff);                   \
    a3 = *(const bf16x8*)(Ab + (wm * 8 + 7) * 512 + foff);                    \
    if ((t) + 2 < NT) {                                                       \
      STAGE_B((t) + 2, Bn);                                                   \
      asm volatile("s_waitcnt vmcnt(4)" ::: "memory");                        \
    } else if ((t) + 1 < NT) {                                                \
      asm volatile("s_waitcnt vmcnt(0)" ::: "memory");                        \
    }                                                                         \
    __builtin_amdgcn_s_barrier();                                             \
    asm volatile("s_waitcnt lgkmcnt(0)" ::: "memory");                        \
    __builtin_amdgcn_s_setprio(1);                                            \
    acc[4][0] = __builtin_amdgcn_mfma_f32_16x16x32_bf16(a0, b0, acc[4][0], 0, 0, 0); \
    acc[4][1] = __builtin_amdgcn_mfma_f32_16x16x32_bf16(a0, b1, acc[4][1], 0, 0, 0); \
    acc[4][2] = __builtin_amdgcn_mfma_f32_16x16x32_bf16(a0, b2, acc[4][2], 0, 0, 0); \
    acc[4][3] = __builtin_amdgcn_mfma_f32_16x16x32_bf16(a0, b3, acc[4][3], 0, 0, 0); \
    acc[5][0] = __builtin_amdgcn_mfma_f32_16x16x32_bf16(a1r, b0, acc[5][0], 0, 0, 0); \
    acc[5][1] = __builtin_amdgcn_mfma_f32_16x16x32_bf16(a1r, b1, acc[5][1], 0, 0, 0); \
    acc[5][2] = __builtin_amdgcn_mfma_f32_16x16x32_bf16(a1r, b2, acc[5][2], 0, 0, 0); \
    acc[5][3] = __builtin_amdgcn_mfma_f32_16x16x32_bf16(a1r, b3, acc[5][3], 0, 0, 0); \
    acc[6][0] = __builtin_amdgcn_mfma_f32_16x16x32_bf16(a2r, b0, acc[6][0], 0, 0, 0); \
    acc[6][1] = __builtin_amdgcn_mfma_f32_16x16x32_bf16(a2r, b1, acc[6][1], 0, 0, 0); \
    acc[6][2] = __builtin_amdgcn_mfma_f32_16x16x32_bf16(a2r, b2, acc[6][2], 0, 0, 0); \
    acc[6][3] = __builtin_amdgcn_mfma_f32_16x16x32_bf16(a2r, b3, acc[6][3], 0, 0, 0); \
    acc[7][0] = __builtin_amdgcn_mfma_f32_16x16x32_bf16(a3, b0, acc[7][0], 0, 0, 0); \
    acc[7][1] = __builtin_amdgcn_mfma_f32_16x16x32_bf16(a3, b1, acc[7][1], 0, 0, 0); \
    acc[7][2] = __builtin_amdgcn_mfma_f32_16x16x32_bf16(a3, b2, acc[7][2], 0, 0, 0); \
    acc[7][3] = __builtin_amdgcn_mfma_f32_16x16x32_bf16(a3, b3, acc[7][3], 0, 0, 0); \
    __builtin_amdgcn_s_setprio(0);                                            \
  } while (0)

  // prologue: stage tiles 0,1; wait tile 0 complete; barrier
  STAGE_A(0, As0); STAGE_B(0, Bs0);
  STAGE_A(1, As1); STAGE_B(1, Bs1);
  asm volatile("s_waitcnt vmcnt(4)" ::: "memory");
  __builtin_amdgcn_s_barrier();

  for (int tb = 0; tb < NT; tb += 3) {
    TILE(tb, As0, Bs0, As2, Bs2);
    if (tb + 1 < NT) TILE(tb + 1, As1, Bs1, As0, Bs0);
    if (tb + 2 < NT) TILE(tb + 2, As2, Bs2, As1, Bs1);
  }
#undef TILE
#undef STAGE_A
#undef STAGE_B

  const int crow = (lane >> 4) * 4;
  const int ccol = lane & 15;
#pragma unroll
  for (int i = 0; i < 8; ++i) {
#pragma unroll
    for (int j = 0; j < 4; ++j) {
      int r0 = m0 + wm * 128 + i * 16 + crow;
      int c = n0 + wn * 64 + j * 16 + ccol;
      float bb = HAS_BIAS ? bias[c] : 0.f;
#pragma unroll
      for (int t = 0; t < 4; ++t) {
        float v = acc[i][j][t] + bb;
        if (DO_TANH) v = tanhf(v);
        size_t idx = (size_t)bz * sC + (size_t)(r0 + t) * ldc + c;
        if (OUT_F32) ((float*)Cout)[idx] = v;
        else ((u16*)Cout)[idx] = f2bf(v);
      }
    }
  }
}

// ---------------- softmax over keys with +v bias and mask ----------------
__global__ __launch_bounds__(256) void softmax_rows(const float* __restrict__ logits,
                                                    const float* __restrict__ vbias,
                                                    const int* __restrict__ amask,
                                                    u16* __restrict__ P) {
  const int row = blockIdx.x;
  const int b = row >> 10;
  const float* lg = logits + (size_t)row * LSEQ;
  u16* prow = P + (size_t)row * LSEQ;
  const int tid = threadIdx.x;
  float x[4];
  int mk[4];
  float vmax = -3.0e38f;
#pragma unroll
  for (int i = 0; i < 4; ++i) {
    int k = tid + i * 256;
    mk[i] = amask[(b << 10) + k];
    x[i] = lg[k] + vbias[(b << 10) + k];
    if (!mk[i]) x[i] = -3.0e38f;
    vmax = fmaxf(vmax, x[i]);
  }
#pragma unroll
  for (int o = 32; o; o >>= 1) vmax = fmaxf(vmax, __shfl_xor(vmax, o));
  __shared__ float sred[4];
  if ((tid & 63) == 0) sred[tid >> 6] = vmax;
  __syncthreads();
  vmax = fmaxf(fmaxf(sred[0], sred[1]), fmaxf(sred[2], sred[3]));
  float s = 0.f, e[4];
#pragma unroll
  for (int i = 0; i < 4; ++i) {
    e[i] = mk[i] ? __expf(x[i] - vmax) : 0.f;
    s += e[i];
  }
#pragma unroll
  for (int o = 32; o; o >>= 1) s += __shfl_xor(s, o);
  __shared__ float ssum[4];
  if ((tid & 63) == 0) ssum[tid >> 6] = s;
  __syncthreads();
  s = (ssum[0] + ssum[1]) + (ssum[2] + ssum[3]);
  float inv = 1.f / s;
#pragma unroll
  for (int i = 0; i < 4; ++i) prow[tid + i * 256] = f2bf(e[i] * inv);
}

// ---------------- masked pooling ----------------
__global__ __launch_bounds__(256) void pool_partial(const u16* __restrict__ outfc,
                                                    const int* __restrict__ amask,
                                                    float* __restrict__ partial,
                                                    float* __restrict__ pcount) {
  int d = blockIdx.x * 256 + threadIdx.x;
  int qc = blockIdx.y;
  int b = blockIdx.z;
  const u16* base = outfc + (((size_t)b * LSEQ + qc * 128) * DDIM) + d;
  const int* mrow = amask + b * LSEQ + qc * 128;
  float s = 0.f;
  int cnt = 0;
  for (int q = 0; q < 128; ++q) {
    if (mrow[q]) {
      s += bf2f(base[(size_t)q * DDIM]);
      cnt++;
    }
  }
  partial[((size_t)b * 8 + qc) * DDIM + d] = s;
  if (threadIdx.x == 0 && blockIdx.x == 0) pcount[b * 8 + qc] = (float)cnt;
}

__global__ __launch_bounds__(256) void pool_final(const float* __restrict__ partial,
                                                  const float* __restrict__ pcount,
                                                  float* __restrict__ out) {
  int idx = blockIdx.x * 256 + threadIdx.x;
  int b = idx >> 10;
  int d = idx & 1023;
  float s = 0.f, len = 0.f;
#pragma unroll
  for (int qc = 0; qc < 8; ++qc) {
    s += partial[((size_t)b * 8 + qc) * DDIM + d];
    len += pcount[b * 8 + qc];
  }
  out[idx] = s / len;
}

extern "C" void kernel_launch(void* const* d_in, const int* in_sizes, int n_in,
                              void* d_out, int out_size, void* d_ws, size_t ws_size,
                              hipStream_t stream) {
  const float* output = (const float*)d_in[0];
  const float* context = (const float*)d_in[1];
  const int* amask = (const int*)d_in[2];
  const float* Wo = (const float*)d_in[3];
  const float* bo = (const float*)d_in[4];
  const float* Wc = (const float*)d_in[5];
  const float* Wb = (const float*)d_in[7];
  const float* Wv = (const float*)d_in[10];
  const float* Wf = (const float*)d_in[12];
  const float* bfb = (const float*)d_in[13];
  float* out = (float*)d_out;
  (void)n_in; (void)in_sizes; (void)out_size;

  const size_t LD2 = (size_t)LSEQ * DDIM * 2;
  const size_t fixed_b = (size_t)22 * (1 << 20);
  const size_t per_b = 4 * LD2 + (size_t)LSEQ * LSEQ * 4 + LSEQ * 4 + 4096;
  int G = 1;
  for (int g : {32, 16, 8, 4, 2, 1}) {
    if (fixed_b + (size_t)g * per_b <= ws_size) { G = g; break; }
  }
  const int NG = BATCH / G;

  char* ws = (char*)d_ws;
  size_t off = 0;
  auto alloc = [&](size_t bytes) {
    char* p = ws + off;
    off += (bytes + 255) & ~(size_t)255;
    return p;
  };
  const size_t W2 = (size_t)DDIM * DDIM * 2;
  u16* wb_bf = (u16*)alloc(W2);
  u16* wf_bf = (u16*)alloc(2 * W2);
  u16* woT_bf = (u16*)alloc(W2);
  u16* wcT_bf = (u16*)alloc(W2);
  u16* wboT_bf = (u16*)alloc(W2);
  u16* mt_bf = (u16*)alloc(W2);
  float* bbo = (float*)alloc(DDIM * 4);
  float* wv2 = (float*)alloc(DDIM * 4);
  float* partial = (float*)alloc((size_t)BATCH * 8 * DDIM * 4);
  float* pcount = (float*)alloc((size_t)BATCH * 8 * 4);
  u16* out_g = (u16*)alloc((size_t)G * LD2);
  u16* ctx_g = (u16*)alloc((size_t)G * LD2);
  u16* ctxT_g = (u16*)alloc((size_t)G * LD2);
  u16* y_g = (u16*)alloc((size_t)G * LD2);
  float* logits = (float*)alloc((size_t)G * LSEQ * LSEQ * 4);
  float* vbuf = (float*)alloc((size_t)G * LSEQ * 4);

  dim3 blk(256), blk8(512);
  const long long M1 = (long long)LSEQ * DDIM;
  const int BIG = 1 << 30;

  // ---- weight precompute ----
  cvt_kernel<<<dim3(1024), blk, 0, stream>>>(Wb, wb_bf, DDIM * DDIM / 4);
  cvt_kernel<<<dim3(2048), blk, 0, stream>>>(Wf, wf_bf, DDIM * 2 * DDIM / 4);
  transpose_cv<<<dim3(16, 16, 1), blk, 0, stream>>>(Wo, woT_bf, nullptr);
  transpose_cv<<<dim3(16, 16, 1), blk, 0, stream>>>(Wc, wcT_bf, nullptr);
  rowdot_kernel<<<dim3(1024), blk, 0, stream>>>(Wb, bo, bbo);
  w2_kernel<<<dim3(4), blk, 0, stream>>>(Wv, bbo, Wc, wv2);
  gemm_nt<0, 0, 0, 0><<<dim3(64), blk, 0, stream>>>(
      woT_bf, woT_bf, BIG, wb_bf, nullptr, wboT_bf,
      1024, 1024, 1024, 1024, 0, 0, 0, 8, 8, 1);
  gemm_nt<0, 0, 0, 0><<<dim3(64), blk, 0, stream>>>(
      wcT_bf, wcT_bf, BIG, wboT_bf, nullptr, mt_bf,
      1024, 1024, 1024, 1024, 0, 0, 0, 8, 8, 1);

  for (int grp = 0; grp < NG; ++grp) {
    const int gb = grp * G;
    const float* outp = output + (size_t)gb * LSEQ * DDIM;
    const float* ctxp = context + (size_t)gb * LSEQ * DDIM;
    const int* amp = amask + (size_t)gb * LSEQ;
    const int n4 = G * LSEQ * DDIM / 4;

    cvt_kernel<<<dim3(n4 / 256), blk, 0, stream>>>(outp, out_g, n4);
    transpose_cv<<<dim3(16, 16, G), blk, 0, stream>>>(ctxp, ctxT_g, ctx_g);
    rowdot_kernel<<<dim3(G * LSEQ), blk, 0, stream>>>(ctxp, wv2, vbuf);

    // y = output @ M
    gemm256<0, 0, 0, 0><<<dim3(G * 16), blk8, 0, stream>>>(
        out_g, out_g, BIG, mt_bf, nullptr, y_g,
        1024, 1024, 1024, 1024, 0, 0, 0, G * 4, 4, 1);
    // logits[b] = y[b] @ ctx[b]^T
    gemm256<1, 0, 0, 1><<<dim3(G * 16), blk8, 0, stream>>>(
        y_g, y_g, BIG, ctx_g, nullptr, logits,
        1024, 1024, 1024, 1024, M1, M1, M1, 4, 4, G);
    // P = softmax(logits + wv2.ctx + mask) -> bf16 into y_g
    softmax_rows<<<dim3(G * LSEQ), blk, 0, stream>>>(logits, vbuf, amp, y_g);
    // mix[b] = P[b] @ ctxT[b]^T -> into ctx_g
    gemm256<0, 0, 0, 1><<<dim3(G * 16), blk8, 0, stream>>>(
        y_g, y_g, BIG, ctxT_g, nullptr, ctx_g,
        1024, 1024, 1024, 1024, M1, M1, M1, 4, 4, G);
    // fc: tanh([output, mix] @ Wf^T + bf) -> bf16 into y_g
    gemm256<0, 1, 1, 0><<<dim3(G * 16), blk8, 0, stream>>>(
        out_g, ctx_g, 1024, wf_bf, bfb, y_g,
        2048, 1024, 2048, 1024, 0, 0, 0, G * 4, 4, 1);
    pool_partial<<<dim3(4, 8, G), blk, 0, stream>>>(
        y_g, amp, partial + (size_t)gb * 8 * DDIM, pcount + (size_t)gb * 8);
  }
  pool_final<<<dim3(128), blk, 0, stream>>>(partial, pcount, out);
}